// Round 1
// baseline (3798.766 us; speedup 1.0000x reference)
//
#include <hip/hip_runtime.h>
#include <hip/hip_bf16.h>

// Problem constants
#define B_    2
#define QN    100
#define NP    6
#define WS2   49
#define CC    256
#define NHH   8
#define HDD   32
#define NWIN  600            // Q*Np windows per batch
#define O_PER_B 7526400      // NH*WS2*NWIN*HD

// ws layout (bytes): xT fp32 [2*64*64*256] | qkv bf16 [1200*768*50] | O fp32 [2*O_PER_B]
#define XT_BYTES   8388608
#define QKV_BYTES  92160000

__device__ __forceinline__ float bf2f(unsigned short u) {
  union { unsigned int i; float f; } v; v.i = ((unsigned int)u) << 16; return v.f;
}
__device__ __forceinline__ unsigned short f2bf(float f) {
  union { float f; unsigned int i; } v; v.f = f;
  unsigned int x = v.i;
  x += 0x7fffu + ((x >> 16) & 1u);   // round-to-nearest-even
  return (unsigned short)(x >> 16);
}

// ---------- K0: x (B,C,H,W) -> xT (B,H*W,C) ----------
__global__ void k0_transpose(const float* __restrict__ x, float* __restrict__ xT) {
  __shared__ float tile[32][33];
  int b  = blockIdx.z;
  int hw0 = blockIdx.x * 32;
  int c0  = blockIdx.y * 32;
  const float* src = x + (size_t)b * CC * 4096;
  float* dst = xT + (size_t)b * 4096 * CC;
  #pragma unroll
  for (int i = threadIdx.y; i < 32; i += 8)
    tile[i][threadIdx.x] = src[(size_t)(c0 + i) * 4096 + hw0 + threadIdx.x];
  __syncthreads();
  #pragma unroll
  for (int i = threadIdx.y; i < 32; i += 8)
    dst[(size_t)(hw0 + i) * CC + c0 + threadIdx.x] = tile[threadIdx.x][i];
}

// ---------- K1: per-window sample + QKV GEMM -> qkv_ws (bf16, [win][j<768][r<50]) ----------
__launch_bounds__(256, 3)
__global__ void k1_sample_qkv(const float* __restrict__ xT,
                              const float* __restrict__ polys,
                              const float* __restrict__ w_qkv,
                              const float* __restrict__ b_qkv,
                              unsigned short* __restrict__ qkv_ws) {
  __shared__ float sp[WS2 * CC];
  __shared__ float co_x0[WS2], co_y0[WS2], co_wx[WS2], co_wy[WS2];
  const int tid = threadIdx.x;
  const int m = blockIdx.x;
  const int b = blockIdx.y;

  // Phase A: coords for the 49 rows of this window (grid scramble: n = m*49+r)
  if (tid < WS2) {
    int n = m * WS2 + tid;
    int q = n / (WS2 * NP);
    int p = (n / NP) % WS2;
    int a = n % NP;
    const float* pc = polys + (size_t)(b * QN + q) * 12;
    float al = (float)a * 0.2f;
    float py = pc[0];
    float px = pc[6];
    #pragma unroll
    for (int i = 1; i < 6; i++) { py = py * al + pc[i]; px = px * al + pc[6 + i]; }
    py = 2.0f * py - 1.0f;
    px = 2.0f * px - 1.0f;
    // mesh: delta[k] = 2*(-4 + k*7/6)/64 ; mesh_y uses p/7, mesh_x uses p%7
    float gy = py + (2.0f * (-4.0f + (float)(p / 7) * (7.0f / 6.0f))) * (1.0f / 64.0f);
    float gx = px + (2.0f * (-4.0f + (float)(p % 7) * (7.0f / 6.0f))) * (1.0f / 64.0f);
    // NOTE the reference swap: fx from grid_y, fy from grid_x
    float fx = (gy + 1.0f) * 0.5f * 63.0f;
    float fy = (gx + 1.0f) * 0.5f * 63.0f;
    float x0 = floorf(fx), y0 = floorf(fy);
    co_x0[tid] = x0; co_y0[tid] = y0;
    co_wx[tid] = fx - x0; co_wy[tid] = fy - y0;
  }
  __syncthreads();

  // Phase B: bilinear sampling, thread = channel, loop rows (coalesced 1KB loads)
  const float* xb = xT + (size_t)b * (4096 * CC);
  for (int r = 0; r < WS2; r++) {
    float x0 = co_x0[r], y0 = co_y0[r];
    float wx = co_wx[r], wy = co_wy[r];
    float x1 = x0 + 1.0f, y1 = y0 + 1.0f;
    int xi0 = (int)fminf(fmaxf(x0, 0.0f), 63.0f);
    int yi0 = (int)fminf(fmaxf(y0, 0.0f), 63.0f);
    int xi1 = (int)fminf(fmaxf(x1, 0.0f), 63.0f);
    int yi1 = (int)fminf(fmaxf(y1, 0.0f), 63.0f);
    bool vx0 = (x0 >= 0.0f) && (x0 <= 63.0f);
    bool vx1 = (x1 >= 0.0f) && (x1 <= 63.0f);
    bool vy0 = (y0 >= 0.0f) && (y0 <= 63.0f);
    bool vy1 = (y1 >= 0.0f) && (y1 <= 63.0f);
    float v00 = (vx0 && vy0) ? xb[(yi0 * 64 + xi0) * CC + tid] : 0.0f;
    float v01 = (vx1 && vy0) ? xb[(yi0 * 64 + xi1) * CC + tid] : 0.0f;
    float v10 = (vx0 && vy1) ? xb[(yi1 * 64 + xi0) * CC + tid] : 0.0f;
    float v11 = (vx1 && vy1) ? xb[(yi1 * 64 + xi1) * CC + tid] : 0.0f;
    sp[r * CC + tid] = v00 * (1.0f - wy) * (1.0f - wx) + v01 * (1.0f - wy) * wx
                     + v10 * wy * (1.0f - wx) + v11 * wy * wx;
  }
  __syncthreads();

  // Phase C: QKV GEMM. Thread owns one output column j (3 rounds of 256),
  // 49 row-accumulators in registers; sp reads are wave-uniform (broadcast b128).
  const size_t wbase = (size_t)(b * NWIN + m) * (768 * 50);
  for (int jr = 0; jr < 3; jr++) {
    int j = jr * 256 + tid;
    const float4* wrow = (const float4*)(w_qkv + (size_t)j * CC);
    float acc[WS2];
    float bias = b_qkv[j];
    #pragma unroll
    for (int r = 0; r < WS2; r++) acc[r] = bias;
    for (int c4 = 0; c4 < 64; c4++) {
      float4 wv = wrow[c4];
      const float4* sp4 = ((const float4*)sp) + c4;
      #pragma unroll
      for (int r = 0; r < WS2; r++) {
        float4 s = sp4[r * 64];
        acc[r] += s.x * wv.x + s.y * wv.y + s.z * wv.z + s.w * wv.w;
      }
    }
    unsigned short* qd = qkv_ws + wbase + (size_t)j * 50;
    #pragma unroll
    for (int r = 0; r < WS2; r++) qd[r] = f2bf(acc[r]);
  }
}

// ---------- K2: per-window attention -> O workspace in scrambled [b][h][p][m][d] order ----------
__launch_bounds__(256, 4)
__global__ void k2_attn(const unsigned short* __restrict__ qkv_ws,
                        const float* __restrict__ pos_bias,
                        float* __restrict__ o_ws) {
  __shared__ float qkvT[96 * 50];   // [local row l][r], l: 0-31 q, 32-63 k, 64-95 v
  __shared__ float Smat[WS2 * WS2];
  __shared__ float pb[WS2];
  const int tid = threadIdx.x;
  const int m = blockIdx.x;
  const int b = blockIdx.y;
  if (tid < WS2) pb[tid] = pos_bias[tid];
  const unsigned short* wsrc = qkv_ws + (size_t)(b * NWIN + m) * (768 * 50);
  const float scale = 0.17677669529663687f;  // 1/sqrt(32)

  for (int h = 0; h < NHH; h++) {
    __syncthreads();
    // stage q,k,v for head h (96 rows of 50 bf16, read as dwords)
    for (int idx = tid; idx < 96 * 25; idx += 256) {
      int l = idx / 25;
      int pr = idx % 25;
      int j = (l >> 5) * 256 + h * HDD + (l & 31);
      unsigned int u = *(const unsigned int*)(wsrc + (size_t)j * 50 + 2 * pr);
      qkvT[l * 50 + 2 * pr]     = bf2f((unsigned short)(u & 0xffffu));
      qkvT[l * 50 + 2 * pr + 1] = bf2f((unsigned short)(u >> 16));  // r=49 slot unused
    }
    __syncthreads();
    // S[p][r2] = scale * q[p]·k[r2] + pos_bias[p]
    for (int it = tid; it < WS2 * WS2; it += 256) {
      int p = it / WS2, r2 = it % WS2;
      float acc = 0.0f;
      #pragma unroll
      for (int d = 0; d < HDD; d++)
        acc += qkvT[d * 50 + p] * qkvT[(HDD + d) * 50 + r2];
      Smat[it] = acc * scale + pb[p];
    }
    __syncthreads();
    // softmax over r2 (row-wise), one thread per row
    if (tid < WS2) {
      float* row = Smat + tid * WS2;
      float mx = row[0];
      for (int t2 = 1; t2 < WS2; t2++) mx = fmaxf(mx, row[t2]);
      float ssum = 0.0f;
      for (int t2 = 0; t2 < WS2; t2++) { float e = expf(row[t2] - mx); row[t2] = e; ssum += e; }
      float inv = 1.0f / ssum;
      for (int t2 = 0; t2 < WS2; t2++) row[t2] *= inv;
    }
    __syncthreads();
    // O[p][d] = sum_r P[p][r] * v[r][d]; store in scrambled order ((h*49+p)*600+m)*32+d
    for (int it = tid; it < WS2 * HDD; it += 256) {
      int p = it >> 5, d = it & 31;
      float acc = 0.0f;
      #pragma unroll
      for (int r2 = 0; r2 < WS2; r2++)
        acc += Smat[p * WS2 + r2] * qkvT[(64 + d) * 50 + r2];
      o_ws[(size_t)b * O_PER_B + (size_t)(((h * WS2 + p) * NWIN + m) * HDD + d)] = acc;
    }
  }
}

// ---------- K3: conv (49-tap over p') + projection ----------
__global__ void k3_conv_proj(const float* __restrict__ o_ws,
                             const float* __restrict__ conv_w,
                             const float* __restrict__ conv_b,
                             const float* __restrict__ w_proj,
                             const float* __restrict__ b_proj,
                             float* __restrict__ out) {
  __shared__ float yv[CC];
  __shared__ float cw[WS2];
  const int tid = threadIdx.x;
  const int np = blockIdx.x;   // n' in [0,600)
  const int b = blockIdx.y;
  if (tid < WS2) cw[tid] = conv_w[tid];
  __syncthreads();
  // O reinterpretation: chunk [n'*12544, +12544) == [p'][c'] tile (contiguous)
  const float* base = o_ws + (size_t)b * O_PER_B + (size_t)np * (WS2 * CC);
  float acc = conv_b[0];
  for (int p = 0; p < WS2; p++)
    acc += cw[p] * base[p * CC + tid];
  yv[tid] = acc;
  __syncthreads();
  const float4* y4 = (const float4*)yv;
  const float4* w4 = (const float4*)(w_proj + (size_t)tid * CC);
  float s = b_proj[tid];
  float s2 = 0.0f;
  #pragma unroll 8
  for (int c4 = 0; c4 < 64; c4++) {
    float4 a = y4[c4], wv = w4[c4];
    s2 += a.x * wv.x + a.y * wv.y + a.z * wv.z + a.w * wv.w;
  }
  out[((size_t)(b * NWIN + np)) * CC + tid] = s + s2;
}

extern "C" void kernel_launch(void* const* d_in, const int* in_sizes, int n_in,
                              void* d_out, int out_size, void* d_ws, size_t ws_size,
                              hipStream_t stream) {
  const float* x        = (const float*)d_in[0];
  const float* polys    = (const float*)d_in[1];
  const float* w_qkv    = (const float*)d_in[2];
  const float* b_qkv    = (const float*)d_in[3];
  const float* w_proj   = (const float*)d_in[4];
  const float* b_proj   = (const float*)d_in[5];
  const float* conv_w   = (const float*)d_in[6];
  const float* conv_b   = (const float*)d_in[7];
  const float* pos_bias = (const float*)d_in[8];
  float* out = (float*)d_out;

  char* ws = (char*)d_ws;
  float* xT = (float*)ws;
  unsigned short* qkv_ws = (unsigned short*)(ws + XT_BYTES);
  float* o_ws = (float*)(ws + XT_BYTES + QKV_BYTES);

  hipLaunchKernelGGL(k0_transpose, dim3(128, 8, 2), dim3(32, 8), 0, stream, x, xT);
  hipLaunchKernelGGL(k1_sample_qkv, dim3(NWIN, B_), dim3(256), 0, stream,
                     xT, polys, w_qkv, b_qkv, qkv_ws);
  hipLaunchKernelGGL(k2_attn, dim3(NWIN, B_), dim3(256), 0, stream,
                     qkv_ws, pos_bias, o_ws);
  hipLaunchKernelGGL(k3_conv_proj, dim3(NWIN, B_), dim3(256), 0, stream,
                     o_ws, conv_w, conv_b, w_proj, b_proj, out);
}

// Round 2
// 987.258 us; speedup vs baseline: 3.8478x; 3.8478x over previous
//
#include <hip/hip_runtime.h>
#include <hip/hip_bf16.h>

// Problem constants
#define B_    2
#define QN    100
#define NP    6
#define WS2   49
#define CC    256
#define NHH   8
#define HDD   32
#define NWIN  600            // Q*Np windows per batch
#define O_PER_B 7526400      // NH*WS2*NWIN*HD

// ws layout (bytes): xT fp32 [2*64*64*256] | qkv bf16 [1200][49][768] | O fp32 [2*O_PER_B]
// qkv layout is r-major so wave stores are 128B-contiguous (round-1 fix: the
// j-major layout caused 2B partial-line scatter -> 12.5 GB HBM writeback).
#define XT_BYTES   8388608
#define QKV_SHORTS_PER_WIN (WS2 * 768)      // 37632 shorts = 75264 B
#define QKV_BYTES  (1200 * WS2 * 768 * 2)   // 90316800

__device__ __forceinline__ float bf2f(unsigned short u) {
  union { unsigned int i; float f; } v; v.i = ((unsigned int)u) << 16; return v.f;
}
__device__ __forceinline__ unsigned short f2bf(float f) {
  union { float f; unsigned int i; } v; v.f = f;
  unsigned int x = v.i;
  x += 0x7fffu + ((x >> 16) & 1u);   // round-to-nearest-even
  return (unsigned short)(x >> 16);
}

// ---------- K0: x (B,C,H,W) -> xT (B,H*W,C) ----------
__global__ void k0_transpose(const float* __restrict__ x, float* __restrict__ xT) {
  __shared__ float tile[32][33];
  int b  = blockIdx.z;
  int hw0 = blockIdx.x * 32;
  int c0  = blockIdx.y * 32;
  const float* src = x + (size_t)b * CC * 4096;
  float* dst = xT + (size_t)b * 4096 * CC;
  #pragma unroll
  for (int i = threadIdx.y; i < 32; i += 8)
    tile[i][threadIdx.x] = src[(size_t)(c0 + i) * 4096 + hw0 + threadIdx.x];
  __syncthreads();
  #pragma unroll
  for (int i = threadIdx.y; i < 32; i += 8)
    dst[(size_t)(hw0 + i) * CC + c0 + threadIdx.x] = tile[threadIdx.x][i];
}

// ---------- K1: per-window sample + QKV GEMM -> qkv_ws (bf16, [win][r][j]) ----------
__launch_bounds__(256, 3)
__global__ void k1_sample_qkv(const float* __restrict__ xT,
                              const float* __restrict__ polys,
                              const float* __restrict__ w_qkv,
                              const float* __restrict__ b_qkv,
                              unsigned short* __restrict__ qkv_ws) {
  __shared__ float sp[WS2 * CC];
  __shared__ float co_x0[WS2], co_y0[WS2], co_wx[WS2], co_wy[WS2];
  const int tid = threadIdx.x;
  const int m = blockIdx.x;
  const int b = blockIdx.y;

  // Phase A: coords for the 49 rows of this window (grid scramble: n = m*49+r)
  if (tid < WS2) {
    int n = m * WS2 + tid;
    int q = n / (WS2 * NP);
    int p = (n / NP) % WS2;
    int a = n % NP;
    const float* pc = polys + (size_t)(b * QN + q) * 12;
    float al = (float)a * 0.2f;
    float py = pc[0];
    float px = pc[6];
    #pragma unroll
    for (int i = 1; i < 6; i++) { py = py * al + pc[i]; px = px * al + pc[6 + i]; }
    py = 2.0f * py - 1.0f;
    px = 2.0f * px - 1.0f;
    // mesh: delta[k] = 2*(-4 + k*7/6)/64 ; mesh_y uses p/7, mesh_x uses p%7
    float gy = py + (2.0f * (-4.0f + (float)(p / 7) * (7.0f / 6.0f))) * (1.0f / 64.0f);
    float gx = px + (2.0f * (-4.0f + (float)(p % 7) * (7.0f / 6.0f))) * (1.0f / 64.0f);
    // NOTE the reference swap: fx from grid_y, fy from grid_x
    float fx = (gy + 1.0f) * 0.5f * 63.0f;
    float fy = (gx + 1.0f) * 0.5f * 63.0f;
    float x0 = floorf(fx), y0 = floorf(fy);
    co_x0[tid] = x0; co_y0[tid] = y0;
    co_wx[tid] = fx - x0; co_wy[tid] = fy - y0;
  }
  __syncthreads();

  // Phase B: bilinear sampling, thread = channel, loop rows (coalesced 1KB loads)
  const float* xb = xT + (size_t)b * (4096 * CC);
  for (int r = 0; r < WS2; r++) {
    float x0 = co_x0[r], y0 = co_y0[r];
    float wx = co_wx[r], wy = co_wy[r];
    float x1 = x0 + 1.0f, y1 = y0 + 1.0f;
    int xi0 = (int)fminf(fmaxf(x0, 0.0f), 63.0f);
    int yi0 = (int)fminf(fmaxf(y0, 0.0f), 63.0f);
    int xi1 = (int)fminf(fmaxf(x1, 0.0f), 63.0f);
    int yi1 = (int)fminf(fmaxf(y1, 0.0f), 63.0f);
    bool vx0 = (x0 >= 0.0f) && (x0 <= 63.0f);
    bool vx1 = (x1 >= 0.0f) && (x1 <= 63.0f);
    bool vy0 = (y0 >= 0.0f) && (y0 <= 63.0f);
    bool vy1 = (y1 >= 0.0f) && (y1 <= 63.0f);
    float v00 = (vx0 && vy0) ? xb[(yi0 * 64 + xi0) * CC + tid] : 0.0f;
    float v01 = (vx1 && vy0) ? xb[(yi0 * 64 + xi1) * CC + tid] : 0.0f;
    float v10 = (vx0 && vy1) ? xb[(yi1 * 64 + xi0) * CC + tid] : 0.0f;
    float v11 = (vx1 && vy1) ? xb[(yi1 * 64 + xi1) * CC + tid] : 0.0f;
    sp[r * CC + tid] = v00 * (1.0f - wy) * (1.0f - wx) + v01 * (1.0f - wy) * wx
                     + v10 * wy * (1.0f - wx) + v11 * wy * wx;
  }
  __syncthreads();

  // Phase C: QKV GEMM. Thread owns one output column j (3 rounds of 256),
  // 49 row-accumulators in registers; sp reads are wave-uniform (broadcast b128).
  const size_t wbase = (size_t)(b * NWIN + m) * QKV_SHORTS_PER_WIN;
  for (int jr = 0; jr < 3; jr++) {
    int j = jr * 256 + tid;
    const float4* wrow = (const float4*)(w_qkv + (size_t)j * CC);
    float acc[WS2];
    float bias = b_qkv[j];
    #pragma unroll
    for (int r = 0; r < WS2; r++) acc[r] = bias;
    for (int c4 = 0; c4 < 64; c4++) {
      float4 wv = wrow[c4];
      const float4* sp4 = ((const float4*)sp) + c4;
      #pragma unroll
      for (int r = 0; r < WS2; r++) {
        float4 s = sp4[r * 64];
        acc[r] += s.x * wv.x + s.y * wv.y + s.z * wv.z + s.w * wv.w;
      }
    }
    // r-major store: lanes write 64 consecutive shorts = one 128B line per store
    unsigned short* qd = qkv_ws + wbase + j;
    #pragma unroll
    for (int r = 0; r < WS2; r++) qd[(size_t)r * 768] = f2bf(acc[r]);
  }
}

// ---------- K2: per-window attention -> O workspace in scrambled [b][h][p][m][d] order ----------
__launch_bounds__(256, 4)
__global__ void k2_attn(const unsigned short* __restrict__ qkv_ws,
                        const float* __restrict__ pos_bias,
                        float* __restrict__ o_ws) {
  __shared__ float qkvT[96 * 50];   // [local row l][r], l: 0-31 q, 32-63 k, 64-95 v
  __shared__ float Smat[WS2 * WS2];
  __shared__ float pb[WS2];
  const int tid = threadIdx.x;
  const int m = blockIdx.x;
  const int b = blockIdx.y;
  if (tid < WS2) pb[tid] = pos_bias[tid];
  const unsigned short* wsrc = qkv_ws + (size_t)(b * NWIN + m) * QKV_SHORTS_PER_WIN;
  const float scale = 0.17677669529663687f;  // 1/sqrt(32)

  for (int h = 0; h < NHH; h++) {
    __syncthreads();
    // stage q,k,v for head h from [r][j] layout; 8B vector loads.
    // t = (r*3 + s)*8 + lane8 ; j = s*256 + h*32 + lane8*4
    for (int t = tid; t < WS2 * 3 * 8; t += 256) {
      int lane8 = t & 7;
      int seg = t >> 3;
      int r = seg / 3;
      int s = seg % 3;
      const unsigned short* pp = wsrc + (size_t)r * 768 + s * 256 + h * HDD + lane8 * 4;
      uint2 u = *(const uint2*)pp;
      int l = s * 32 + lane8 * 4;
      qkvT[(l + 0) * 50 + r] = bf2f((unsigned short)(u.x & 0xffffu));
      qkvT[(l + 1) * 50 + r] = bf2f((unsigned short)(u.x >> 16));
      qkvT[(l + 2) * 50 + r] = bf2f((unsigned short)(u.y & 0xffffu));
      qkvT[(l + 3) * 50 + r] = bf2f((unsigned short)(u.y >> 16));
    }
    __syncthreads();
    // S[p][r2] = scale * q[p]·k[r2] + pos_bias[p]
    for (int it = tid; it < WS2 * WS2; it += 256) {
      int p = it / WS2, r2 = it % WS2;
      float acc = 0.0f;
      #pragma unroll
      for (int d = 0; d < HDD; d++)
        acc += qkvT[d * 50 + p] * qkvT[(HDD + d) * 50 + r2];
      Smat[it] = acc * scale + pb[p];
    }
    __syncthreads();
    // softmax over r2 (row-wise), one thread per row
    if (tid < WS2) {
      float* row = Smat + tid * WS2;
      float mx = row[0];
      for (int t2 = 1; t2 < WS2; t2++) mx = fmaxf(mx, row[t2]);
      float ssum = 0.0f;
      for (int t2 = 0; t2 < WS2; t2++) { float e = expf(row[t2] - mx); row[t2] = e; ssum += e; }
      float inv = 1.0f / ssum;
      for (int t2 = 0; t2 < WS2; t2++) row[t2] *= inv;
    }
    __syncthreads();
    // O[p][d] = sum_r P[p][r] * v[r][d]; store in scrambled order ((h*49+p)*600+m)*32+d
    for (int it = tid; it < WS2 * HDD; it += 256) {
      int p = it >> 5, d = it & 31;
      float acc = 0.0f;
      #pragma unroll
      for (int r2 = 0; r2 < WS2; r2++)
        acc += Smat[p * WS2 + r2] * qkvT[(64 + d) * 50 + r2];
      o_ws[(size_t)b * O_PER_B + (size_t)(((h * WS2 + p) * NWIN + m) * HDD + d)] = acc;
    }
  }
}

// ---------- K3: conv (49-tap over p') + projection ----------
__global__ void k3_conv_proj(const float* __restrict__ o_ws,
                             const float* __restrict__ conv_w,
                             const float* __restrict__ conv_b,
                             const float* __restrict__ w_proj,
                             const float* __restrict__ b_proj,
                             float* __restrict__ out) {
  __shared__ float yv[CC];
  __shared__ float cw[WS2];
  const int tid = threadIdx.x;
  const int np = blockIdx.x;   // n' in [0,600)
  const int b = blockIdx.y;
  if (tid < WS2) cw[tid] = conv_w[tid];
  __syncthreads();
  // O reinterpretation: chunk [n'*12544, +12544) == [p'][c'] tile (contiguous)
  const float* base = o_ws + (size_t)b * O_PER_B + (size_t)np * (WS2 * CC);
  float acc = conv_b[0];
  for (int p = 0; p < WS2; p++)
    acc += cw[p] * base[p * CC + tid];
  yv[tid] = acc;
  __syncthreads();
  const float4* y4 = (const float4*)yv;
  const float4* w4 = (const float4*)(w_proj + (size_t)tid * CC);
  float s = b_proj[tid];
  float s2 = 0.0f;
  #pragma unroll 8
  for (int c4 = 0; c4 < 64; c4++) {
    float4 a = y4[c4], wv = w4[c4];
    s2 += a.x * wv.x + a.y * wv.y + a.z * wv.z + a.w * wv.w;
  }
  out[((size_t)(b * NWIN + np)) * CC + tid] = s + s2;
}

extern "C" void kernel_launch(void* const* d_in, const int* in_sizes, int n_in,
                              void* d_out, int out_size, void* d_ws, size_t ws_size,
                              hipStream_t stream) {
  const float* x        = (const float*)d_in[0];
  const float* polys    = (const float*)d_in[1];
  const float* w_qkv    = (const float*)d_in[2];
  const float* b_qkv    = (const float*)d_in[3];
  const float* w_proj   = (const float*)d_in[4];
  const float* b_proj   = (const float*)d_in[5];
  const float* conv_w   = (const float*)d_in[6];
  const float* conv_b   = (const float*)d_in[7];
  const float* pos_bias = (const float*)d_in[8];
  float* out = (float*)d_out;

  char* ws = (char*)d_ws;
  float* xT = (float*)ws;
  unsigned short* qkv_ws = (unsigned short*)(ws + XT_BYTES);
  float* o_ws = (float*)(ws + XT_BYTES + QKV_BYTES);

  hipLaunchKernelGGL(k0_transpose, dim3(128, 8, 2), dim3(32, 8), 0, stream, x, xT);
  hipLaunchKernelGGL(k1_sample_qkv, dim3(NWIN, B_), dim3(256), 0, stream,
                     xT, polys, w_qkv, b_qkv, qkv_ws);
  hipLaunchKernelGGL(k2_attn, dim3(NWIN, B_), dim3(256), 0, stream,
                     qkv_ws, pos_bias, o_ws);
  hipLaunchKernelGGL(k3_conv_proj, dim3(NWIN, B_), dim3(256), 0, stream,
                     o_ws, conv_w, conv_b, w_proj, b_proj, out);
}

// Round 3
// 500.610 us; speedup vs baseline: 7.5883x; 1.9721x over previous
//
#include <hip/hip_runtime.h>
#include <hip/hip_bf16.h>

// Problem constants
#define B_    2
#define QN    100
#define NP    6
#define WS2   49
#define CC    256
#define NHH   8
#define HDD   32
#define NWIN  600            // Q*Np windows per batch
#define O_PER_B 7526400      // NH*WS2*NWIN*HD

// ws layout (bytes): xT fp32 | w_qkv bf16 [768][256] | qkv bf16 [1200][49][768] | O fp32
#define XT_BYTES   8388608
#define WB_BYTES   393216
#define QKV_SHORTS_PER_WIN (WS2 * 768)      // 37632 shorts
#define QKV_BYTES  (1200 * WS2 * 768 * 2)   // 90316800

#define SP_LD   260     // sp row stride (floats): 260 mod 32 = 4 -> 2-way-only bank aliasing
#define C_LD    784     // C staging row stride (shorts): 784*2/4 mod 32 = 8 -> conflict-free groups

typedef __attribute__((ext_vector_type(8))) short bf16x8;
typedef __attribute__((ext_vector_type(4))) float f32x4;

__device__ __forceinline__ float bf2f(unsigned short u) {
  union { unsigned int i; float f; } v; v.i = ((unsigned int)u) << 16; return v.f;
}
__device__ __forceinline__ unsigned short f2bf(float f) {
  union { float f; unsigned int i; } v; v.f = f;
  unsigned int x = v.i;
  x += 0x7fffu + ((x >> 16) & 1u);   // round-to-nearest-even
  return (unsigned short)(x >> 16);
}

// ---------- K0: x (B,C,H,W) -> xT (B,H*W,C) ----------
__global__ void k0_transpose(const float* __restrict__ x, float* __restrict__ xT) {
  __shared__ float tile[32][33];
  int b  = blockIdx.z;
  int hw0 = blockIdx.x * 32;
  int c0  = blockIdx.y * 32;
  const float* src = x + (size_t)b * CC * 4096;
  float* dst = xT + (size_t)b * 4096 * CC;
  #pragma unroll
  for (int i = threadIdx.y; i < 32; i += 8)
    tile[i][threadIdx.x] = src[(size_t)(c0 + i) * 4096 + hw0 + threadIdx.x];
  __syncthreads();
  #pragma unroll
  for (int i = threadIdx.y; i < 32; i += 8)
    dst[(size_t)(hw0 + i) * CC + c0 + threadIdx.x] = tile[threadIdx.x][i];
}

// ---------- K05: w_qkv fp32 -> bf16 ----------
__global__ void k05_wcvt(const float* __restrict__ w_qkv, unsigned short* __restrict__ wb) {
  int i = (blockIdx.x * 256 + threadIdx.x) * 4;   // 196608 / 4 = 49152 threads
  float4 v = *(const float4*)(w_qkv + i);
  unsigned short o[4] = { f2bf(v.x), f2bf(v.y), f2bf(v.z), f2bf(v.w) };
  *(uint2*)(wb + i) = *(uint2*)o;
}

// ---------- K1: per-window sample + MFMA QKV GEMM -> qkv_ws (bf16, [win][r][j]) ----------
__launch_bounds__(256, 2)
__global__ void k1_sample_qkv(const float* __restrict__ xT,
                              const float* __restrict__ polys,
                              const unsigned short* __restrict__ wb,
                              const float* __restrict__ b_qkv,
                              unsigned short* __restrict__ qkv_ws) {
  // union: sp [49][260] fp32 (50960 B) lives until A-frags are in registers,
  // then the same region becomes C staging [49][784] bf16 (76832 B)
  __shared__ __align__(16) char uLDS[49 * C_LD * 2];
  __shared__ float co_x0[WS2], co_y0[WS2], co_wx[WS2], co_wy[WS2];
  float* sp = (float*)uLDS;
  unsigned short* Cst = (unsigned short*)uLDS;
  const int tid = threadIdx.x;
  const int m = blockIdx.x;
  const int b = blockIdx.y;

  // Phase A: coords for the 49 rows of this window (grid scramble: n = m*49+r)
  if (tid < WS2) {
    int n = m * WS2 + tid;
    int q = n / (WS2 * NP);
    int p = (n / NP) % WS2;
    int a = n % NP;
    const float* pc = polys + (size_t)(b * QN + q) * 12;
    float al = (float)a * 0.2f;
    float py = pc[0];
    float px = pc[6];
    #pragma unroll
    for (int i = 1; i < 6; i++) { py = py * al + pc[i]; px = px * al + pc[6 + i]; }
    py = 2.0f * py - 1.0f;
    px = 2.0f * px - 1.0f;
    float gy = py + (2.0f * (-4.0f + (float)(p / 7) * (7.0f / 6.0f))) * (1.0f / 64.0f);
    float gx = px + (2.0f * (-4.0f + (float)(p % 7) * (7.0f / 6.0f))) * (1.0f / 64.0f);
    // NOTE the reference swap: fx from grid_y, fy from grid_x
    float fx = (gy + 1.0f) * 0.5f * 63.0f;
    float fy = (gx + 1.0f) * 0.5f * 63.0f;
    float x0 = floorf(fx), y0 = floorf(fy);
    co_x0[tid] = x0; co_y0[tid] = y0;
    co_wx[tid] = fx - x0; co_wy[tid] = fy - y0;
  }
  __syncthreads();

  // Phase B: bilinear sampling, thread = channel, loop rows (coalesced 1KB loads)
  const float* xb = xT + (size_t)b * (4096 * CC);
  for (int r = 0; r < WS2; r++) {
    float x0 = co_x0[r], y0 = co_y0[r];
    float wx = co_wx[r], wy = co_wy[r];
    float x1 = x0 + 1.0f, y1 = y0 + 1.0f;
    int xi0 = (int)fminf(fmaxf(x0, 0.0f), 63.0f);
    int yi0 = (int)fminf(fmaxf(y0, 0.0f), 63.0f);
    int xi1 = (int)fminf(fmaxf(x1, 0.0f), 63.0f);
    int yi1 = (int)fminf(fmaxf(y1, 0.0f), 63.0f);
    bool vx0 = (x0 >= 0.0f) && (x0 <= 63.0f);
    bool vx1 = (x1 >= 0.0f) && (x1 <= 63.0f);
    bool vy0 = (y0 >= 0.0f) && (y0 <= 63.0f);
    bool vy1 = (y1 >= 0.0f) && (y1 <= 63.0f);
    float v00 = (vx0 && vy0) ? xb[(yi0 * 64 + xi0) * CC + tid] : 0.0f;
    float v01 = (vx1 && vy0) ? xb[(yi0 * 64 + xi1) * CC + tid] : 0.0f;
    float v10 = (vx0 && vy1) ? xb[(yi1 * 64 + xi0) * CC + tid] : 0.0f;
    float v11 = (vx1 && vy1) ? xb[(yi1 * 64 + xi1) * CC + tid] : 0.0f;
    sp[r * SP_LD + tid] = v00 * (1.0f - wy) * (1.0f - wx) + v01 * (1.0f - wy) * wx
                        + v10 * wy * (1.0f - wx) + v11 * wy * wx;
  }
  __syncthreads();

  // Phase C1: load all A-fragments into registers (bf16), zero-padded rows 49..63.
  // A-frag layout for mfma_f32_16x16x32_bf16: lane holds A[m=lane&15][k=(lane>>4)*8 + i]
  const int lane = tid & 63;
  const int wv = tid >> 6;        // wave id 0..3 -> N-tile range
  const int lm = lane & 15;
  const int lg = lane >> 4;
  bf16x8 afrag[4][8];
  #pragma unroll
  for (int mt = 0; mt < 4; mt++) {
    int row = mt * 16 + lm;
    bool valid = (row < WS2);
    const float* abase = sp + (valid ? row : 0) * SP_LD;
    #pragma unroll
    for (int ks = 0; ks < 8; ks++) {
      int k0 = ks * 32 + lg * 8;
      float4 lo = *(const float4*)(abase + k0);
      float4 hi = *(const float4*)(abase + k0 + 4);
      union { bf16x8 v; unsigned short u[8]; } t;
      t.u[0] = f2bf(valid ? lo.x : 0.0f);
      t.u[1] = f2bf(valid ? lo.y : 0.0f);
      t.u[2] = f2bf(valid ? lo.z : 0.0f);
      t.u[3] = f2bf(valid ? lo.w : 0.0f);
      t.u[4] = f2bf(valid ? hi.x : 0.0f);
      t.u[5] = f2bf(valid ? hi.y : 0.0f);
      t.u[6] = f2bf(valid ? hi.z : 0.0f);
      t.u[7] = f2bf(valid ? hi.w : 0.0f);
      afrag[mt][ks] = t.v;
    }
  }
  __syncthreads();   // sp dead everywhere -> region becomes C staging

  // Phase C2: MFMA. Wave wv covers N-tiles [wv*12, wv*12+12), all 4 M-tiles.
  // B-frag: lane holds B[n=n0+(lane&15)][k=(lane>>4)*8 + i] from bf16 [768][256].
  for (int nt = 0; nt < 12; nt++) {
    int n0 = (wv * 12 + nt) * 16;
    int ncol = n0 + lm;
    float bias = b_qkv[ncol];
    f32x4 acc[4];
    #pragma unroll
    for (int mt = 0; mt < 4; mt++) acc[mt] = (f32x4){bias, bias, bias, bias};
    const unsigned short* bbase = wb + (size_t)ncol * CC + lg * 8;
    #pragma unroll
    for (int ks = 0; ks < 8; ks++) {
      bf16x8 bfrag = *(const bf16x8*)(bbase + ks * 32);
      #pragma unroll
      for (int mt = 0; mt < 4; mt++)
        acc[mt] = __builtin_amdgcn_mfma_f32_16x16x32_bf16(afrag[mt][ks], bfrag, acc[mt], 0, 0, 0);
    }
    // C/D layout: col = lane&15, row = (lane>>4)*4 + reg
    #pragma unroll
    for (int mt = 0; mt < 4; mt++) {
      int r0 = mt * 16 + lg * 4;
      #pragma unroll
      for (int reg = 0; reg < 4; reg++) {
        int r = r0 + reg;
        if (r < WS2) Cst[r * C_LD + ncol] = f2bf(acc[mt][reg]);
      }
    }
  }
  __syncthreads();

  // Phase D: coalesced copy C staging -> global qkv [win][r][768]
  unsigned short* qd = qkv_ws + (size_t)(b * NWIN + m) * QKV_SHORTS_PER_WIN;
  for (int idx = tid; idx < WS2 * 96; idx += 256) {
    int r = idx / 96;
    int seg = idx % 96;
    *(uint4*)(qd + (size_t)r * 768 + seg * 8) = *(const uint4*)(Cst + r * C_LD + seg * 8);
  }
}

// ---------- K2: per-window attention -> O workspace in scrambled [b][h][p][m][d] order ----------
__launch_bounds__(256, 4)
__global__ void k2_attn(const unsigned short* __restrict__ qkv_ws,
                        const float* __restrict__ pos_bias,
                        float* __restrict__ o_ws) {
  __shared__ float qkvT[96 * 50];   // [local row l][r], l: 0-31 q, 32-63 k, 64-95 v
  __shared__ float Smat[WS2 * WS2];
  __shared__ float pb[WS2];
  const int tid = threadIdx.x;
  const int m = blockIdx.x;
  const int b = blockIdx.y;
  if (tid < WS2) pb[tid] = pos_bias[tid];
  const unsigned short* wsrc = qkv_ws + (size_t)(b * NWIN + m) * QKV_SHORTS_PER_WIN;
  const float scale = 0.17677669529663687f;  // 1/sqrt(32)

  for (int h = 0; h < NHH; h++) {
    __syncthreads();
    // stage q,k,v for head h from [r][j] layout; 8B vector loads.
    for (int t = tid; t < WS2 * 3 * 8; t += 256) {
      int lane8 = t & 7;
      int seg = t >> 3;
      int r = seg / 3;
      int s = seg % 3;
      const unsigned short* pp = wsrc + (size_t)r * 768 + s * 256 + h * HDD + lane8 * 4;
      uint2 u = *(const uint2*)pp;
      int l = s * 32 + lane8 * 4;
      qkvT[(l + 0) * 50 + r] = bf2f((unsigned short)(u.x & 0xffffu));
      qkvT[(l + 1) * 50 + r] = bf2f((unsigned short)(u.x >> 16));
      qkvT[(l + 2) * 50 + r] = bf2f((unsigned short)(u.y & 0xffffu));
      qkvT[(l + 3) * 50 + r] = bf2f((unsigned short)(u.y >> 16));
    }
    __syncthreads();
    // S[p][r2] = scale * q[p]·k[r2] + pos_bias[p]
    for (int it = tid; it < WS2 * WS2; it += 256) {
      int p = it / WS2, r2 = it % WS2;
      float acc = 0.0f;
      #pragma unroll
      for (int d = 0; d < HDD; d++)
        acc += qkvT[d * 50 + p] * qkvT[(HDD + d) * 50 + r2];
      Smat[it] = acc * scale + pb[p];
    }
    __syncthreads();
    // softmax over r2 (row-wise), one thread per row
    if (tid < WS2) {
      float* row = Smat + tid * WS2;
      float mx = row[0];
      for (int t2 = 1; t2 < WS2; t2++) mx = fmaxf(mx, row[t2]);
      float ssum = 0.0f;
      for (int t2 = 0; t2 < WS2; t2++) { float e = expf(row[t2] - mx); row[t2] = e; ssum += e; }
      float inv = 1.0f / ssum;
      for (int t2 = 0; t2 < WS2; t2++) row[t2] *= inv;
    }
    __syncthreads();
    // O[p][d] = sum_r P[p][r] * v[r][d]; store in scrambled order ((h*49+p)*600+m)*32+d
    for (int it = tid; it < WS2 * HDD; it += 256) {
      int p = it >> 5, d = it & 31;
      float acc = 0.0f;
      #pragma unroll
      for (int r2 = 0; r2 < WS2; r2++)
        acc += Smat[p * WS2 + r2] * qkvT[(64 + d) * 50 + r2];
      o_ws[(size_t)b * O_PER_B + (size_t)(((h * WS2 + p) * NWIN + m) * HDD + d)] = acc;
    }
  }
}

// ---------- K3: conv (49-tap over p') + projection ----------
__global__ void k3_conv_proj(const float* __restrict__ o_ws,
                             const float* __restrict__ conv_w,
                             const float* __restrict__ conv_b,
                             const float* __restrict__ w_proj,
                             const float* __restrict__ b_proj,
                             float* __restrict__ out) {
  __shared__ float yv[CC];
  __shared__ float cw[WS2];
  const int tid = threadIdx.x;
  const int np = blockIdx.x;   // n' in [0,600)
  const int b = blockIdx.y;
  if (tid < WS2) cw[tid] = conv_w[tid];
  __syncthreads();
  const float* base = o_ws + (size_t)b * O_PER_B + (size_t)np * (WS2 * CC);
  float acc = conv_b[0];
  for (int p = 0; p < WS2; p++)
    acc += cw[p] * base[p * CC + tid];
  yv[tid] = acc;
  __syncthreads();
  const float4* y4 = (const float4*)yv;
  const float4* w4 = (const float4*)(w_proj + (size_t)tid * CC);
  float s = b_proj[tid];
  float s2 = 0.0f;
  #pragma unroll 8
  for (int c4 = 0; c4 < 64; c4++) {
    float4 a = y4[c4], wv2 = w4[c4];
    s2 += a.x * wv2.x + a.y * wv2.y + a.z * wv2.z + a.w * wv2.w;
  }
  out[((size_t)(b * NWIN + np)) * CC + tid] = s + s2;
}

extern "C" void kernel_launch(void* const* d_in, const int* in_sizes, int n_in,
                              void* d_out, int out_size, void* d_ws, size_t ws_size,
                              hipStream_t stream) {
  const float* x        = (const float*)d_in[0];
  const float* polys    = (const float*)d_in[1];
  const float* w_qkv    = (const float*)d_in[2];
  const float* b_qkv    = (const float*)d_in[3];
  const float* w_proj   = (const float*)d_in[4];
  const float* b_proj   = (const float*)d_in[5];
  const float* conv_w   = (const float*)d_in[6];
  const float* conv_b   = (const float*)d_in[7];
  const float* pos_bias = (const float*)d_in[8];
  float* out = (float*)d_out;

  char* ws = (char*)d_ws;
  float* xT = (float*)ws;
  unsigned short* wb = (unsigned short*)(ws + XT_BYTES);
  unsigned short* qkv_ws = (unsigned short*)(ws + XT_BYTES + WB_BYTES);
  float* o_ws = (float*)(ws + XT_BYTES + WB_BYTES + QKV_BYTES);

  hipLaunchKernelGGL(k0_transpose, dim3(128, 8, 2), dim3(32, 8), 0, stream, x, xT);
  hipLaunchKernelGGL(k05_wcvt, dim3(192), dim3(256), 0, stream, w_qkv, wb);
  hipLaunchKernelGGL(k1_sample_qkv, dim3(NWIN, B_), dim3(256), 0, stream,
                     xT, polys, wb, b_qkv, qkv_ws);
  hipLaunchKernelGGL(k2_attn, dim3(NWIN, B_), dim3(256), 0, stream,
                     qkv_ws, pos_bias, o_ws);
  hipLaunchKernelGGL(k3_conv_proj, dim3(NWIN, B_), dim3(256), 0, stream,
                     o_ws, conv_w, conv_b, w_proj, b_proj, out);
}

// Round 4
// 287.345 us; speedup vs baseline: 13.2202x; 1.7422x over previous
//
#include <hip/hip_runtime.h>
#include <hip/hip_bf16.h>

// Problem constants
#define B_    2
#define QN    100
#define NP    6
#define WS2   49
#define CC    256
#define NHH   8
#define HDD   32
#define NWIN  600            // Q*Np windows per batch
#define O_PER_B 7526400      // NH*WS2*NWIN*HD

// ws layout (bytes): xT fp32 | w_qkv bf16 [768][256] | qkv bf16 [1200][49][768] | O fp32
#define XT_BYTES   8388608
#define WB_BYTES   393216
#define QKV_SHORTS_PER_WIN (WS2 * 768)      // 37632 shorts
#define QKV_BYTES  (1200 * WS2 * 768 * 2)   // 90316800

#define SP_LD   260     // k1 sp row stride (floats)
#define C_LD    784     // k1 C staging row stride (shorts)

typedef __attribute__((ext_vector_type(8))) short bf16x8;
typedef __attribute__((ext_vector_type(4))) float f32x4;

__device__ __forceinline__ float bf2f(unsigned short u) {
  union { unsigned int i; float f; } v; v.i = ((unsigned int)u) << 16; return v.f;
}
__device__ __forceinline__ unsigned short f2bf(float f) {
  union { float f; unsigned int i; } v; v.f = f;
  unsigned int x = v.i;
  x += 0x7fffu + ((x >> 16) & 1u);   // round-to-nearest-even
  return (unsigned short)(x >> 16);
}

// ---------- K0: x (B,C,H,W) -> xT (B,H*W,C) ----------
__global__ void k0_transpose(const float* __restrict__ x, float* __restrict__ xT) {
  __shared__ float tile[32][33];
  int b  = blockIdx.z;
  int hw0 = blockIdx.x * 32;
  int c0  = blockIdx.y * 32;
  const float* src = x + (size_t)b * CC * 4096;
  float* dst = xT + (size_t)b * 4096 * CC;
  #pragma unroll
  for (int i = threadIdx.y; i < 32; i += 8)
    tile[i][threadIdx.x] = src[(size_t)(c0 + i) * 4096 + hw0 + threadIdx.x];
  __syncthreads();
  #pragma unroll
  for (int i = threadIdx.y; i < 32; i += 8)
    dst[(size_t)(hw0 + i) * CC + c0 + threadIdx.x] = tile[threadIdx.x][i];
}

// ---------- K05: w_qkv fp32 -> bf16 ----------
__global__ void k05_wcvt(const float* __restrict__ w_qkv, unsigned short* __restrict__ wb) {
  int i = (blockIdx.x * 256 + threadIdx.x) * 4;
  float4 v = *(const float4*)(w_qkv + i);
  unsigned short o[4] = { f2bf(v.x), f2bf(v.y), f2bf(v.z), f2bf(v.w) };
  *(uint2*)(wb + i) = *(uint2*)o;
}

// ---------- K1: per-window sample + MFMA QKV GEMM -> qkv_ws (bf16, [win][r][j]) ----------
__launch_bounds__(256, 2)
__global__ void k1_sample_qkv(const float* __restrict__ xT,
                              const float* __restrict__ polys,
                              const unsigned short* __restrict__ wb,
                              const float* __restrict__ b_qkv,
                              unsigned short* __restrict__ qkv_ws) {
  __shared__ __align__(16) char uLDS[49 * C_LD * 2];
  __shared__ float co_x0[WS2], co_y0[WS2], co_wx[WS2], co_wy[WS2];
  float* sp = (float*)uLDS;
  unsigned short* Cst = (unsigned short*)uLDS;
  const int tid = threadIdx.x;
  const int m = blockIdx.x;
  const int b = blockIdx.y;

  if (tid < WS2) {
    int n = m * WS2 + tid;
    int q = n / (WS2 * NP);
    int p = (n / NP) % WS2;
    int a = n % NP;
    const float* pc = polys + (size_t)(b * QN + q) * 12;
    float al = (float)a * 0.2f;
    float py = pc[0];
    float px = pc[6];
    #pragma unroll
    for (int i = 1; i < 6; i++) { py = py * al + pc[i]; px = px * al + pc[6 + i]; }
    py = 2.0f * py - 1.0f;
    px = 2.0f * px - 1.0f;
    float gy = py + (2.0f * (-4.0f + (float)(p / 7) * (7.0f / 6.0f))) * (1.0f / 64.0f);
    float gx = px + (2.0f * (-4.0f + (float)(p % 7) * (7.0f / 6.0f))) * (1.0f / 64.0f);
    // NOTE the reference swap: fx from grid_y, fy from grid_x
    float fx = (gy + 1.0f) * 0.5f * 63.0f;
    float fy = (gx + 1.0f) * 0.5f * 63.0f;
    float x0 = floorf(fx), y0 = floorf(fy);
    co_x0[tid] = x0; co_y0[tid] = y0;
    co_wx[tid] = fx - x0; co_wy[tid] = fy - y0;
  }
  __syncthreads();

  const float* xb = xT + (size_t)b * (4096 * CC);
  for (int r = 0; r < WS2; r++) {
    float x0 = co_x0[r], y0 = co_y0[r];
    float wx = co_wx[r], wy = co_wy[r];
    float x1 = x0 + 1.0f, y1 = y0 + 1.0f;
    int xi0 = (int)fminf(fmaxf(x0, 0.0f), 63.0f);
    int yi0 = (int)fminf(fmaxf(y0, 0.0f), 63.0f);
    int xi1 = (int)fminf(fmaxf(x1, 0.0f), 63.0f);
    int yi1 = (int)fminf(fmaxf(y1, 0.0f), 63.0f);
    bool vx0 = (x0 >= 0.0f) && (x0 <= 63.0f);
    bool vx1 = (x1 >= 0.0f) && (x1 <= 63.0f);
    bool vy0 = (y0 >= 0.0f) && (y0 <= 63.0f);
    bool vy1 = (y1 >= 0.0f) && (y1 <= 63.0f);
    float v00 = (vx0 && vy0) ? xb[(yi0 * 64 + xi0) * CC + tid] : 0.0f;
    float v01 = (vx1 && vy0) ? xb[(yi0 * 64 + xi1) * CC + tid] : 0.0f;
    float v10 = (vx0 && vy1) ? xb[(yi1 * 64 + xi0) * CC + tid] : 0.0f;
    float v11 = (vx1 && vy1) ? xb[(yi1 * 64 + xi1) * CC + tid] : 0.0f;
    sp[r * SP_LD + tid] = v00 * (1.0f - wy) * (1.0f - wx) + v01 * (1.0f - wy) * wx
                        + v10 * wy * (1.0f - wx) + v11 * wy * wx;
  }
  __syncthreads();

  // A-frags into registers (bf16), zero-padded rows 49..63
  const int lane = tid & 63;
  const int wv = tid >> 6;
  const int lm = lane & 15;
  const int lg = lane >> 4;
  bf16x8 afrag[4][8];
  #pragma unroll
  for (int mt = 0; mt < 4; mt++) {
    int row = mt * 16 + lm;
    bool valid = (row < WS2);
    const float* abase = sp + (valid ? row : 0) * SP_LD;
    #pragma unroll
    for (int ks = 0; ks < 8; ks++) {
      int k0 = ks * 32 + lg * 8;
      float4 lo = *(const float4*)(abase + k0);
      float4 hi = *(const float4*)(abase + k0 + 4);
      union { bf16x8 v; unsigned short u[8]; } t;
      t.u[0] = f2bf(valid ? lo.x : 0.0f);
      t.u[1] = f2bf(valid ? lo.y : 0.0f);
      t.u[2] = f2bf(valid ? lo.z : 0.0f);
      t.u[3] = f2bf(valid ? lo.w : 0.0f);
      t.u[4] = f2bf(valid ? hi.x : 0.0f);
      t.u[5] = f2bf(valid ? hi.y : 0.0f);
      t.u[6] = f2bf(valid ? hi.z : 0.0f);
      t.u[7] = f2bf(valid ? hi.w : 0.0f);
      afrag[mt][ks] = t.v;
    }
  }
  __syncthreads();

  for (int nt = 0; nt < 12; nt++) {
    int n0 = (wv * 12 + nt) * 16;
    int ncol = n0 + lm;
    float bias = b_qkv[ncol];
    f32x4 acc[4];
    #pragma unroll
    for (int mt = 0; mt < 4; mt++) acc[mt] = (f32x4){bias, bias, bias, bias};
    const unsigned short* bbase = wb + (size_t)ncol * CC + lg * 8;
    #pragma unroll
    for (int ks = 0; ks < 8; ks++) {
      bf16x8 bfrag = *(const bf16x8*)(bbase + ks * 32);
      #pragma unroll
      for (int mt = 0; mt < 4; mt++)
        acc[mt] = __builtin_amdgcn_mfma_f32_16x16x32_bf16(afrag[mt][ks], bfrag, acc[mt], 0, 0, 0);
    }
    #pragma unroll
    for (int mt = 0; mt < 4; mt++) {
      int r0 = mt * 16 + lg * 4;
      #pragma unroll
      for (int reg = 0; reg < 4; reg++) {
        int r = r0 + reg;
        if (r < WS2) Cst[r * C_LD + ncol] = f2bf(acc[mt][reg]);
      }
    }
  }
  __syncthreads();

  unsigned short* qd = qkv_ws + (size_t)(b * NWIN + m) * QKV_SHORTS_PER_WIN;
  for (int idx = tid; idx < WS2 * 96; idx += 256) {
    int r = idx / 96;
    int seg = idx % 96;
    *(uint4*)(qd + (size_t)r * 768 + seg * 8) = *(const uint4*)(Cst + r * C_LD + seg * 8);
  }
}

// ---------- K2: MFMA windowed attention, wave-per-head (2 heads/wave) ----------
// S = QK^T via mfma (K=32 exact), in-register shfl softmax (pos_bias cancels),
// P -> LDS (C-layout -> A-layout transform), O = PV via mfma, direct store.
#define P_LD 72    // P row stride in shorts (16B-aligned frag reads, 2-way-max bank alias)
#define V_LD 72    // Vt row stride in shorts
__launch_bounds__(256, 2)
__global__ void k2_attn(const unsigned short* __restrict__ qkv_ws,
                        float* __restrict__ o_ws) {
  __shared__ __align__(16) unsigned short Pbuf[4][64 * P_LD];   // 4 x 9216 B
  __shared__ __align__(16) unsigned short Vbuf[4][32 * V_LD];   // 4 x 4608 B
  const int tid = threadIdx.x;
  const int lane = tid & 63;
  const int wv = tid >> 6;
  const int lm = lane & 15;
  const int lg = lane >> 4;
  const int m = blockIdx.x;
  const int b = blockIdx.y;
  const unsigned short* wsrc = qkv_ws + (size_t)(b * NWIN + m) * QKV_SHORTS_PER_WIN;
  const float scale = 0.17677669529663687f;  // 1/sqrt(32)
  unsigned short* P  = Pbuf[wv];
  unsigned short* Vt = Vbuf[wv];

  for (int hh = 0; hh < 2; hh++) {
    const int h = wv * 2 + hh;

    // Stage V^T into LDS: Vt[d][r], rows 49..63 zeroed (so padded K-dim of PV is 0*0)
    {
      int dd = lane & 31;
      int rb = lane >> 5;
      #pragma unroll
      for (int i = 0; i < 32; i++) {
        int rr = i * 2 + rb;
        unsigned short val = 0;
        if (rr < WS2) val = wsrc[(size_t)rr * 768 + 512 + h * HDD + dd];
        Vt[dd * V_LD + rr] = val;
      }
    }

    // Q/K fragments straight from global [r][j] (d-contiguous = frag layout), row-clamped
    bf16x8 qf[4], kf[4];
    #pragma unroll
    for (int t = 0; t < 4; t++) {
      int r = t * 16 + lm; if (r > 48) r = 48;
      qf[t] = *(const bf16x8*)(wsrc + (size_t)r * 768 + h * HDD + lg * 8);
      kf[t] = *(const bf16x8*)(wsrc + (size_t)r * 768 + 256 + h * HDD + lg * 8);
    }

    // S = Q K^T  (C-layout: col r2 = nt*16+lm, row p = mt*16 + lg*4 + reg)
    f32x4 s[4][4];
    #pragma unroll
    for (int mt = 0; mt < 4; mt++)
      #pragma unroll
      for (int nt = 0; nt < 4; nt++) {
        s[mt][nt] = (f32x4){0.f, 0.f, 0.f, 0.f};
        s[mt][nt] = __builtin_amdgcn_mfma_f32_16x16x32_bf16(qf[mt], kf[nt], s[mt][nt], 0, 0, 0);
      }

    // scale + mask invalid key columns (only nt=3, lm>0 -> r2 in 49..63)
    #pragma unroll
    for (int mt = 0; mt < 4; mt++)
      #pragma unroll
      for (int nt = 0; nt < 4; nt++) {
        bool badcol = (nt == 3) && (lm > 0);
        #pragma unroll
        for (int reg = 0; reg < 4; reg++)
          s[mt][nt][reg] = badcol ? -1e30f : s[mt][nt][reg] * scale;
      }

    // softmax over keys: per (mt,reg) row, reduce across nt frags + 16-lane lm group
    #pragma unroll
    for (int mt = 0; mt < 4; mt++) {
      #pragma unroll
      for (int reg = 0; reg < 4; reg++) {
        float mx = fmaxf(fmaxf(s[mt][0][reg], s[mt][1][reg]),
                         fmaxf(s[mt][2][reg], s[mt][3][reg]));
        #pragma unroll
        for (int off = 1; off < 16; off <<= 1) mx = fmaxf(mx, __shfl_xor(mx, off));
        float sum = 0.0f;
        #pragma unroll
        for (int nt = 0; nt < 4; nt++) {
          float e = __expf(s[mt][nt][reg] - mx);
          s[mt][nt][reg] = e;
          sum += e;
        }
        #pragma unroll
        for (int off = 1; off < 16; off <<= 1) sum += __shfl_xor(sum, off);
        float inv = 1.0f / sum;
        #pragma unroll
        for (int nt = 0; nt < 4; nt++) s[mt][nt][reg] *= inv;
      }
    }

    // P (bf16) -> LDS row-major [p][r2] (C->A layout transform)
    #pragma unroll
    for (int mt = 0; mt < 4; mt++)
      #pragma unroll
      for (int nt = 0; nt < 4; nt++)
        #pragma unroll
        for (int reg = 0; reg < 4; reg++)
          P[(mt * 16 + lg * 4 + reg) * P_LD + nt * 16 + lm] = f2bf(s[mt][nt][reg]);

    // O = P V  (M=p 4 tiles, N=d 2 tiles, K=r2 2 steps)
    f32x4 o[4][2];
    #pragma unroll
    for (int mt = 0; mt < 4; mt++)
      #pragma unroll
      for (int nt2 = 0; nt2 < 2; nt2++) o[mt][nt2] = (f32x4){0.f, 0.f, 0.f, 0.f};
    #pragma unroll
    for (int ks = 0; ks < 2; ks++) {
      bf16x8 vf[2];
      #pragma unroll
      for (int nt2 = 0; nt2 < 2; nt2++)
        vf[nt2] = *(const bf16x8*)(Vt + (nt2 * 16 + lm) * V_LD + ks * 32 + lg * 8);
      #pragma unroll
      for (int mt = 0; mt < 4; mt++) {
        bf16x8 af = *(const bf16x8*)(P + (mt * 16 + lm) * P_LD + ks * 32 + lg * 8);
        #pragma unroll
        for (int nt2 = 0; nt2 < 2; nt2++)
          o[mt][nt2] = __builtin_amdgcn_mfma_f32_16x16x32_bf16(af, vf[nt2], o[mt][nt2], 0, 0, 0);
      }
    }

    // store O: o_ws[b][((h*49+p)*600+m)*32+d], C-layout rows p = mt*16+lg*4+reg
    float* ob = o_ws + (size_t)b * O_PER_B + ((size_t)h * WS2 * NWIN + m) * HDD;
    #pragma unroll
    for (int mt = 0; mt < 4; mt++)
      #pragma unroll
      for (int reg = 0; reg < 4; reg++) {
        int p = mt * 16 + lg * 4 + reg;
        if (p < WS2) {
          #pragma unroll
          for (int nt2 = 0; nt2 < 2; nt2++)
            ob[(size_t)p * (NWIN * HDD) + nt2 * 16 + lm] = o[mt][nt2][reg];
        }
      }
  }
}

// ---------- K3: conv (49-tap over p') + projection ----------
__global__ void k3_conv_proj(const float* __restrict__ o_ws,
                             const float* __restrict__ conv_w,
                             const float* __restrict__ conv_b,
                             const float* __restrict__ w_proj,
                             const float* __restrict__ b_proj,
                             float* __restrict__ out) {
  __shared__ float yv[CC];
  __shared__ float cw[WS2];
  const int tid = threadIdx.x;
  const int np = blockIdx.x;
  const int b = blockIdx.y;
  if (tid < WS2) cw[tid] = conv_w[tid];
  __syncthreads();
  const float* base = o_ws + (size_t)b * O_PER_B + (size_t)np * (WS2 * CC);
  float acc = conv_b[0];
  for (int p = 0; p < WS2; p++)
    acc += cw[p] * base[p * CC + tid];
  yv[tid] = acc;
  __syncthreads();
  const float4* y4 = (const float4*)yv;
  const float4* w4 = (const float4*)(w_proj + (size_t)tid * CC);
  float s = b_proj[tid];
  float s2 = 0.0f;
  #pragma unroll 8
  for (int c4 = 0; c4 < 64; c4++) {
    float4 a = y4[c4], wv2 = w4[c4];
    s2 += a.x * wv2.x + a.y * wv2.y + a.z * wv2.z + a.w * wv2.w;
  }
  out[((size_t)(b * NWIN + np)) * CC + tid] = s + s2;
}

extern "C" void kernel_launch(void* const* d_in, const int* in_sizes, int n_in,
                              void* d_out, int out_size, void* d_ws, size_t ws_size,
                              hipStream_t stream) {
  const float* x        = (const float*)d_in[0];
  const float* polys    = (const float*)d_in[1];
  const float* w_qkv    = (const float*)d_in[2];
  const float* b_qkv    = (const float*)d_in[3];
  const float* w_proj   = (const float*)d_in[4];
  const float* b_proj   = (const float*)d_in[5];
  const float* conv_w   = (const float*)d_in[6];
  const float* conv_b   = (const float*)d_in[7];
  float* out = (float*)d_out;

  char* ws = (char*)d_ws;
  float* xT = (float*)ws;
  unsigned short* wb = (unsigned short*)(ws + XT_BYTES);
  unsigned short* qkv_ws = (unsigned short*)(ws + XT_BYTES + WB_BYTES);
  float* o_ws = (float*)(ws + XT_BYTES + WB_BYTES + QKV_BYTES);

  hipLaunchKernelGGL(k0_transpose, dim3(128, 8, 2), dim3(32, 8), 0, stream, x, xT);
  hipLaunchKernelGGL(k05_wcvt, dim3(192), dim3(256), 0, stream, w_qkv, wb);
  hipLaunchKernelGGL(k1_sample_qkv, dim3(NWIN, B_), dim3(256), 0, stream,
                     xT, polys, wb, b_qkv, qkv_ws);
  hipLaunchKernelGGL(k2_attn, dim3(NWIN, B_), dim3(256), 0, stream,
                     qkv_ws, o_ws);
  hipLaunchKernelGGL(k3_conv_proj, dim3(NWIN, B_), dim3(256), 0, stream,
                     o_ws, conv_w, conv_b, w_proj, b_proj, out);
}

// Round 5
// 280.230 us; speedup vs baseline: 13.5559x; 1.0254x over previous
//
#include <hip/hip_runtime.h>
#include <hip/hip_bf16.h>

// Problem constants
#define B_    2
#define QN    100
#define NP    6
#define WS2   49
#define CC    256
#define NHH   8
#define HDD   32
#define NWIN  600            // Q*Np windows per batch
#define O_PER_B 7526400      // NH*WS2*NWIN*HD

// ws layout (bytes): xT fp32 | w_qkv bf16 [768][256] | qkv bf16 [1200][49][768] | O fp32
#define XT_BYTES   8388608
#define WB_BYTES   393216
#define QKV_SHORTS_PER_WIN (WS2 * 768)      // 37632 shorts
#define QKV_BYTES  (1200 * WS2 * 768 * 2)   // 90316800

#define SPB_LD 264   // bf16 sp row stride (shorts): 132 dwords = 4 mod 32 -> balanced b128 reads

typedef __attribute__((ext_vector_type(8))) short bf16x8;
typedef __attribute__((ext_vector_type(4))) float f32x4;

__device__ __forceinline__ float bf2f(unsigned short u) {
  union { unsigned int i; float f; } v; v.i = ((unsigned int)u) << 16; return v.f;
}
__device__ __forceinline__ unsigned short f2bf(float f) {
  union { float f; unsigned int i; } v; v.f = f;
  unsigned int x = v.i;
  x += 0x7fffu + ((x >> 16) & 1u);   // round-to-nearest-even
  return (unsigned short)(x >> 16);
}

// ---------- K0: x (B,C,H,W) -> xT (B,H*W,C) ----------
__global__ void k0_transpose(const float* __restrict__ x, float* __restrict__ xT) {
  __shared__ float tile[32][33];
  int b  = blockIdx.z;
  int hw0 = blockIdx.x * 32;
  int c0  = blockIdx.y * 32;
  const float* src = x + (size_t)b * CC * 4096;
  float* dst = xT + (size_t)b * 4096 * CC;
  #pragma unroll
  for (int i = threadIdx.y; i < 32; i += 8)
    tile[i][threadIdx.x] = src[(size_t)(c0 + i) * 4096 + hw0 + threadIdx.x];
  __syncthreads();
  #pragma unroll
  for (int i = threadIdx.y; i < 32; i += 8)
    dst[(size_t)(hw0 + i) * CC + c0 + threadIdx.x] = tile[threadIdx.x][i];
}

// ---------- K05: w_qkv fp32 -> bf16 ----------
__global__ void k05_wcvt(const float* __restrict__ w_qkv, unsigned short* __restrict__ wb) {
  int i = (blockIdx.x * 256 + threadIdx.x) * 4;
  float4 v = *(const float4*)(w_qkv + i);
  unsigned short o[4] = { f2bf(v.x), f2bf(v.y), f2bf(v.z), f2bf(v.w) };
  *(uint2*)(wb + i) = *(uint2*)o;
}

// ---------- K1: per-window sample + MFMA QKV GEMM -> qkv_ws (bf16, [win][r][j]) ----------
// Round-4 restructure: sp held as bf16 (34 KB LDS total), no C staging (direct
// b16 global stores, L2 merges 32B segments), nt split in halves so acc+afrag
// fit 3 waves/SIMD -> 12 waves/CU (was 8, latency-bound at OccupancyPercent 17).
__launch_bounds__(256, 3)
__global__ void k1_sample_qkv(const float* __restrict__ xT,
                              const float* __restrict__ polys,
                              const unsigned short* __restrict__ wb,
                              const float* __restrict__ b_qkv,
                              unsigned short* __restrict__ qkv_ws) {
  __shared__ __align__(16) unsigned short spb[64 * SPB_LD];   // rows 49..63 zeroed
  __shared__ float co_x0[WS2], co_y0[WS2], co_wx[WS2], co_wy[WS2];
  const int tid = threadIdx.x;
  const int m = blockIdx.x;
  const int b = blockIdx.y;

  // Phase A: coords for the 49 rows of this window (grid scramble: n = m*49+r)
  if (tid < WS2) {
    int n = m * WS2 + tid;
    int q = n / (WS2 * NP);
    int p = (n / NP) % WS2;
    int a = n % NP;
    const float* pc = polys + (size_t)(b * QN + q) * 12;
    float al = (float)a * 0.2f;
    float py = pc[0];
    float px = pc[6];
    #pragma unroll
    for (int i = 1; i < 6; i++) { py = py * al + pc[i]; px = px * al + pc[6 + i]; }
    py = 2.0f * py - 1.0f;
    px = 2.0f * px - 1.0f;
    float gy = py + (2.0f * (-4.0f + (float)(p / 7) * (7.0f / 6.0f))) * (1.0f / 64.0f);
    float gx = px + (2.0f * (-4.0f + (float)(p % 7) * (7.0f / 6.0f))) * (1.0f / 64.0f);
    // NOTE the reference swap: fx from grid_y, fy from grid_x
    float fx = (gy + 1.0f) * 0.5f * 63.0f;
    float fy = (gx + 1.0f) * 0.5f * 63.0f;
    float x0 = floorf(fx), y0 = floorf(fy);
    co_x0[tid] = x0; co_y0[tid] = y0;
    co_wx[tid] = fx - x0; co_wy[tid] = fy - y0;
  }
  // zero pad rows 49..63 (so padded-M A-frags contribute 0 to MFMA)
  {
    unsigned int* z = (unsigned int*)(spb + WS2 * SPB_LD);
    for (int i = tid; i < 15 * SPB_LD / 2; i += 256) z[i] = 0u;
  }
  __syncthreads();

  // Phase B: bilinear sampling, thread = channel; write bf16 (same rounding as
  // the old A-frag f2bf, so precision-identical)
  const float* xb = xT + (size_t)b * (4096 * CC);
  for (int r = 0; r < WS2; r++) {
    float x0 = co_x0[r], y0 = co_y0[r];
    float wx = co_wx[r], wy = co_wy[r];
    float x1 = x0 + 1.0f, y1 = y0 + 1.0f;
    int xi0 = (int)fminf(fmaxf(x0, 0.0f), 63.0f);
    int yi0 = (int)fminf(fmaxf(y0, 0.0f), 63.0f);
    int xi1 = (int)fminf(fmaxf(x1, 0.0f), 63.0f);
    int yi1 = (int)fminf(fmaxf(y1, 0.0f), 63.0f);
    bool vx0 = (x0 >= 0.0f) && (x0 <= 63.0f);
    bool vx1 = (x1 >= 0.0f) && (x1 <= 63.0f);
    bool vy0 = (y0 >= 0.0f) && (y0 <= 63.0f);
    bool vy1 = (y1 >= 0.0f) && (y1 <= 63.0f);
    float v00 = (vx0 && vy0) ? xb[(yi0 * 64 + xi0) * CC + tid] : 0.0f;
    float v01 = (vx1 && vy0) ? xb[(yi0 * 64 + xi1) * CC + tid] : 0.0f;
    float v10 = (vx0 && vy1) ? xb[(yi1 * 64 + xi0) * CC + tid] : 0.0f;
    float v11 = (vx1 && vy1) ? xb[(yi1 * 64 + xi1) * CC + tid] : 0.0f;
    float s = v00 * (1.0f - wy) * (1.0f - wx) + v01 * (1.0f - wy) * wx
            + v10 * wy * (1.0f - wx) + v11 * wy * wx;
    spb[r * SPB_LD + tid] = f2bf(s);
  }
  __syncthreads();

  // Phase C: MFMA GEMM, wave wv owns N-columns [wv*192, +192), split in 2
  // halves of 6 N-tiles (acc = 96 VGPRs live; A-frags re-read per ks from LDS).
  const int lane = tid & 63;
  const int wv = tid >> 6;
  const int lm = lane & 15;
  const int lg = lane >> 4;
  unsigned short* qd = qkv_ws + (size_t)(b * NWIN + m) * QKV_SHORTS_PER_WIN;

  #pragma unroll
  for (int half = 0; half < 2; half++) {
    const int ncol0 = (wv * 12 + half * 6) * 16 + lm;
    f32x4 acc[4][6];
    #pragma unroll
    for (int j6 = 0; j6 < 6; j6++) {
      float bias = b_qkv[ncol0 + j6 * 16];
      #pragma unroll
      for (int mt = 0; mt < 4; mt++) acc[mt][j6] = (f32x4){bias, bias, bias, bias};
    }
    #pragma unroll
    for (int ks = 0; ks < 8; ks++) {
      bf16x8 af[4];
      #pragma unroll
      for (int mt = 0; mt < 4; mt++)
        af[mt] = *(const bf16x8*)(spb + (mt * 16 + lm) * SPB_LD + ks * 32 + lg * 8);
      #pragma unroll
      for (int j6 = 0; j6 < 6; j6++) {
        bf16x8 bfrag = *(const bf16x8*)(wb + (size_t)(ncol0 + j6 * 16) * CC + ks * 32 + lg * 8);
        #pragma unroll
        for (int mt = 0; mt < 4; mt++)
          acc[mt][j6] = __builtin_amdgcn_mfma_f32_16x16x32_bf16(af[mt], bfrag, acc[mt][j6], 0, 0, 0);
      }
    }
    // direct store, C-layout rows r = mt*16 + lg*4 + reg, col = ncol
    #pragma unroll
    for (int mt = 0; mt < 4; mt++) {
      #pragma unroll
      for (int reg = 0; reg < 4; reg++) {
        int r = mt * 16 + lg * 4 + reg;
        if (r < WS2) {
          #pragma unroll
          for (int j6 = 0; j6 < 6; j6++)
            qd[(size_t)r * 768 + ncol0 + j6 * 16] = f2bf(acc[mt][j6][reg]);
        }
      }
    }
  }
}

// ---------- K2: MFMA windowed attention, wave-per-head (2 heads/wave) ----------
#define P_LD 72    // P row stride in shorts
#define V_LD 72    // Vt row stride in shorts
__launch_bounds__(256, 2)
__global__ void k2_attn(const unsigned short* __restrict__ qkv_ws,
                        float* __restrict__ o_ws) {
  __shared__ __align__(16) unsigned short Pbuf[4][64 * P_LD];
  __shared__ __align__(16) unsigned short Vbuf[4][32 * V_LD];
  const int tid = threadIdx.x;
  const int lane = tid & 63;
  const int wv = tid >> 6;
  const int lm = lane & 15;
  const int lg = lane >> 4;
  const int m = blockIdx.x;
  const int b = blockIdx.y;
  const unsigned short* wsrc = qkv_ws + (size_t)(b * NWIN + m) * QKV_SHORTS_PER_WIN;
  const float scale = 0.17677669529663687f;  // 1/sqrt(32)
  unsigned short* P  = Pbuf[wv];
  unsigned short* Vt = Vbuf[wv];

  for (int hh = 0; hh < 2; hh++) {
    const int h = wv * 2 + hh;

    // Stage V^T into LDS: Vt[d][r], rows 49..63 zeroed
    {
      int dd = lane & 31;
      int rb = lane >> 5;
      #pragma unroll
      for (int i = 0; i < 32; i++) {
        int rr = i * 2 + rb;
        unsigned short val = 0;
        if (rr < WS2) val = wsrc[(size_t)rr * 768 + 512 + h * HDD + dd];
        Vt[dd * V_LD + rr] = val;
      }
    }

    // Q/K fragments straight from global [r][j], row-clamped
    bf16x8 qf[4], kf[4];
    #pragma unroll
    for (int t = 0; t < 4; t++) {
      int r = t * 16 + lm; if (r > 48) r = 48;
      qf[t] = *(const bf16x8*)(wsrc + (size_t)r * 768 + h * HDD + lg * 8);
      kf[t] = *(const bf16x8*)(wsrc + (size_t)r * 768 + 256 + h * HDD + lg * 8);
    }

    // S = Q K^T
    f32x4 s[4][4];
    #pragma unroll
    for (int mt = 0; mt < 4; mt++)
      #pragma unroll
      for (int nt = 0; nt < 4; nt++) {
        s[mt][nt] = (f32x4){0.f, 0.f, 0.f, 0.f};
        s[mt][nt] = __builtin_amdgcn_mfma_f32_16x16x32_bf16(qf[mt], kf[nt], s[mt][nt], 0, 0, 0);
      }

    #pragma unroll
    for (int mt = 0; mt < 4; mt++)
      #pragma unroll
      for (int nt = 0; nt < 4; nt++) {
        bool badcol = (nt == 3) && (lm > 0);
        #pragma unroll
        for (int reg = 0; reg < 4; reg++)
          s[mt][nt][reg] = badcol ? -1e30f : s[mt][nt][reg] * scale;
      }

    // softmax over keys (pos_bias is per-row constant: cancels exactly)
    #pragma unroll
    for (int mt = 0; mt < 4; mt++) {
      #pragma unroll
      for (int reg = 0; reg < 4; reg++) {
        float mx = fmaxf(fmaxf(s[mt][0][reg], s[mt][1][reg]),
                         fmaxf(s[mt][2][reg], s[mt][3][reg]));
        #pragma unroll
        for (int off = 1; off < 16; off <<= 1) mx = fmaxf(mx, __shfl_xor(mx, off));
        float sum = 0.0f;
        #pragma unroll
        for (int nt = 0; nt < 4; nt++) {
          float e = __expf(s[mt][nt][reg] - mx);
          s[mt][nt][reg] = e;
          sum += e;
        }
        #pragma unroll
        for (int off = 1; off < 16; off <<= 1) sum += __shfl_xor(sum, off);
        float inv = 1.0f / sum;
        #pragma unroll
        for (int nt = 0; nt < 4; nt++) s[mt][nt][reg] *= inv;
      }
    }

    // P (bf16) -> LDS row-major [p][r2]
    #pragma unroll
    for (int mt = 0; mt < 4; mt++)
      #pragma unroll
      for (int nt = 0; nt < 4; nt++)
        #pragma unroll
        for (int reg = 0; reg < 4; reg++)
          P[(mt * 16 + lg * 4 + reg) * P_LD + nt * 16 + lm] = f2bf(s[mt][nt][reg]);

    // O = P V
    f32x4 o[4][2];
    #pragma unroll
    for (int mt = 0; mt < 4; mt++)
      #pragma unroll
      for (int nt2 = 0; nt2 < 2; nt2++) o[mt][nt2] = (f32x4){0.f, 0.f, 0.f, 0.f};
    #pragma unroll
    for (int ks = 0; ks < 2; ks++) {
      bf16x8 vf[2];
      #pragma unroll
      for (int nt2 = 0; nt2 < 2; nt2++)
        vf[nt2] = *(const bf16x8*)(Vt + (nt2 * 16 + lm) * V_LD + ks * 32 + lg * 8);
      #pragma unroll
      for (int mt = 0; mt < 4; mt++) {
        bf16x8 af = *(const bf16x8*)(P + (mt * 16 + lm) * P_LD + ks * 32 + lg * 8);
        #pragma unroll
        for (int nt2 = 0; nt2 < 2; nt2++)
          o[mt][nt2] = __builtin_amdgcn_mfma_f32_16x16x32_bf16(af, vf[nt2], o[mt][nt2], 0, 0, 0);
      }
    }

    // store O: o_ws[b][((h*49+p)*600+m)*32+d]
    float* ob = o_ws + (size_t)b * O_PER_B + ((size_t)h * WS2 * NWIN + m) * HDD;
    #pragma unroll
    for (int mt = 0; mt < 4; mt++)
      #pragma unroll
      for (int reg = 0; reg < 4; reg++) {
        int p = mt * 16 + lg * 4 + reg;
        if (p < WS2) {
          #pragma unroll
          for (int nt2 = 0; nt2 < 2; nt2++)
            ob[(size_t)p * (NWIN * HDD) + nt2 * 16 + lm] = o[mt][nt2][reg];
        }
      }
  }
}

// ---------- K3: conv (49-tap over p') + projection ----------
__global__ void k3_conv_proj(const float* __restrict__ o_ws,
                             const float* __restrict__ conv_w,
                             const float* __restrict__ conv_b,
                             const float* __restrict__ w_proj,
                             const float* __restrict__ b_proj,
                             float* __restrict__ out) {
  __shared__ float yv[CC];
  __shared__ float cw[WS2];
  const int tid = threadIdx.x;
  const int np = blockIdx.x;
  const int b = blockIdx.y;
  if (tid < WS2) cw[tid] = conv_w[tid];
  __syncthreads();
  const float* base = o_ws + (size_t)b * O_PER_B + (size_t)np * (WS2 * CC);
  float acc = conv_b[0];
  for (int p = 0; p < WS2; p++)
    acc += cw[p] * base[p * CC + tid];
  yv[tid] = acc;
  __syncthreads();
  const float4* y4 = (const float4*)yv;
  const float4* w4 = (const float4*)(w_proj + (size_t)tid * CC);
  float s = b_proj[tid];
  float s2 = 0.0f;
  #pragma unroll 8
  for (int c4 = 0; c4 < 64; c4++) {
    float4 a = y4[c4], wv2 = w4[c4];
    s2 += a.x * wv2.x + a.y * wv2.y + a.z * wv2.z + a.w * wv2.w;
  }
  out[((size_t)(b * NWIN + np)) * CC + tid] = s + s2;
}

extern "C" void kernel_launch(void* const* d_in, const int* in_sizes, int n_in,
                              void* d_out, int out_size, void* d_ws, size_t ws_size,
                              hipStream_t stream) {
  const float* x        = (const float*)d_in[0];
  const float* polys    = (const float*)d_in[1];
  const float* w_qkv    = (const float*)d_in[2];
  const float* b_qkv    = (const float*)d_in[3];
  const float* w_proj   = (const float*)d_in[4];
  const float* b_proj   = (const float*)d_in[5];
  const float* conv_w   = (const float*)d_in[6];
  const float* conv_b   = (const float*)d_in[7];
  float* out = (float*)d_out;

  char* ws = (char*)d_ws;
  float* xT = (float*)ws;
  unsigned short* wb = (unsigned short*)(ws + XT_BYTES);
  unsigned short* qkv_ws = (unsigned short*)(ws + XT_BYTES + WB_BYTES);
  float* o_ws = (float*)(ws + XT_BYTES + WB_BYTES + QKV_BYTES);

  hipLaunchKernelGGL(k0_transpose, dim3(128, 8, 2), dim3(32, 8), 0, stream, x, xT);
  hipLaunchKernelGGL(k05_wcvt, dim3(192), dim3(256), 0, stream, w_qkv, wb);
  hipLaunchKernelGGL(k1_sample_qkv, dim3(NWIN, B_), dim3(256), 0, stream,
                     xT, polys, wb, b_qkv, qkv_ws);
  hipLaunchKernelGGL(k2_attn, dim3(NWIN, B_), dim3(256), 0, stream,
                     qkv_ws, o_ws);
  hipLaunchKernelGGL(k3_conv_proj, dim3(NWIN, B_), dim3(256), 0, stream,
                     o_ws, conv_w, conv_b, w_proj, b_proj, out);
}